// Round 1
// baseline (1710.927 us; speedup 1.0000x reference)
//
#include <hip/hip_runtime.h>
#include <math.h>

typedef float f4 __attribute__((ext_vector_type(4)));

#define D_MODEL 1024
#define N_HEADS 16
#define D_HEAD  64
#define N_BINS  64
#define D_LAT   8

// ---------------------------------------------------------------------------
// SGEMM (NT): C[M,N] = A[M,K] * W[N,K]^T + bias[N]
// 128x128 block tile, BK=16, 256 threads, 8x8 per thread (col split 4+4).
// ---------------------------------------------------------------------------
__global__ __launch_bounds__(256)
void sgemm_nt_bias(const float* __restrict__ A, const float* __restrict__ W,
                   const float* __restrict__ bias, float* __restrict__ C,
                   int M, int N, int K)
{
    __shared__ __attribute__((aligned(16))) float As[16][132];
    __shared__ __attribute__((aligned(16))) float Bs[16][132];

    const int tid = threadIdx.x;
    const int tx = tid & 15;          // 16 col-groups
    const int ty = tid >> 4;          // 16 row-groups
    const int bm = blockIdx.x * 128;
    const int bn = blockIdx.y * 128;

    const int lrow = tid >> 2;        // 0..63
    const int lk   = (tid & 3) * 4;   // 0,4,8,12

    const float* Ap = A + (size_t)(bm + lrow) * K + lk;
    const float* Wp = W + (size_t)(bn + lrow) * K + lk;

    float acc[8][8];
#pragma unroll
    for (int i = 0; i < 8; i++)
#pragma unroll
        for (int j = 0; j < 8; j++) acc[i][j] = 0.f;

    for (int k0 = 0; k0 < K; k0 += 16) {
        f4 a0 = *(const f4*)(Ap + k0);
        f4 a1 = *(const f4*)(Ap + (size_t)64 * K + k0);
        f4 b0 = *(const f4*)(Wp + k0);
        f4 b1 = *(const f4*)(Wp + (size_t)64 * K + k0);

        __syncthreads();
#pragma unroll
        for (int j = 0; j < 4; j++) {
            As[lk + j][lrow]      = a0[j];
            As[lk + j][lrow + 64] = a1[j];
            Bs[lk + j][lrow]      = b0[j];
            Bs[lk + j][lrow + 64] = b1[j];
        }
        __syncthreads();

#pragma unroll
        for (int k = 0; k < 16; k++) {
            f4 ar0 = *(const f4*)&As[k][ty * 8];
            f4 ar1 = *(const f4*)&As[k][ty * 8 + 4];
            f4 br0 = *(const f4*)&Bs[k][tx * 4];
            f4 br1 = *(const f4*)&Bs[k][64 + tx * 4];
#pragma unroll
            for (int i = 0; i < 8; i++) {
                float av = (i < 4) ? ar0[i] : ar1[i - 4];
#pragma unroll
                for (int j = 0; j < 8; j++) {
                    float bv = (j < 4) ? br0[j] : br1[j - 4];
                    acc[i][j] += av * bv;
                }
            }
        }
    }

    f4 bb0 = *(const f4*)&bias[bn + tx * 4];
    f4 bb1 = *(const f4*)&bias[bn + 64 + tx * 4];
#pragma unroll
    for (int i = 0; i < 8; i++) {
        size_t r = (size_t)(bm + ty * 8 + i);
        f4 o0, o1;
#pragma unroll
        for (int j = 0; j < 4; j++) {
            o0[j] = acc[i][j]     + bb0[j];
            o1[j] = acc[i][j + 4] + bb1[j];
        }
        *(f4*)&C[r * N + bn + tx * 4]      = o0;
        *(f4*)&C[r * N + bn + 64 + tx * 4] = o1;
    }
}

// ---------------------------------------------------------------------------
// Bin assignment + soft aggregation.
// grid = (B*H, CH). Each block processes S/CH = 512 key rows of one (b,h),
// in 8 sub-chunks of 64 rows, accumulating partial weighted_K / weighted_V
// (64x64) and counts (64) into `partials`.
// partial layout per (bh,chunk): [Kacc 4096][Vacc 4096][cnt 64] = 8256 floats.
// ---------------------------------------------------------------------------
__global__ __launch_bounds__(256)
void bin_assign_agg(const float* __restrict__ Kbuf, const float* __restrict__ Vbuf,
                    const float* __restrict__ W_bin, const float* __restrict__ proto,
                    const float* __restrict__ log_tau,
                    float* __restrict__ partials, int B, int S)
{
    const int bh = blockIdx.x;
    const int h  = bh & (N_HEADS - 1);
    const int b  = bh >> 4;
    const int chunk = blockIdx.y;
    const int CH = gridDim.y;
    const int tid = threadIdx.x;

    __shared__ __attribute__((aligned(16))) float Wb[8][64];     // W_bin[l][d]
    __shared__ __attribute__((aligned(16))) float Prt[8][64];    // proto^T [l][n]
    __shared__ __attribute__((aligned(16))) float zsm[64][8];
    __shared__ __attribute__((aligned(16))) float Kt[64][68];
    __shared__ __attribute__((aligned(16))) float Vt[64][68];
    __shared__ __attribute__((aligned(16))) float Pt[64][68];

    if (tid < 128) {
        ((f4*)&Wb[0][0])[tid] = ((const f4*)W_bin)[tid];
    } else {
        int t = tid - 128;
        f4 p = ((const f4*)(proto + (size_t)h * N_BINS * D_LAT))[t];
        int n = t >> 1, l4 = (t & 1) * 4;
        Prt[l4 + 0][n] = p[0];
        Prt[l4 + 1][n] = p[1];
        Prt[l4 + 2][n] = p[2];
        Prt[l4 + 3][n] = p[3];
    }
    const float tau   = fmaxf(expf(log_tau[h]), 1e-3f);
    const float scale = 1.0f / (tau + 1e-8f);

    const int row = tid >> 2, sub = tid & 3;          // 4 lanes per key row
    const int n0 = (tid >> 4) * 4, d0 = (tid & 15) * 4; // 4x4 acc cell

    float accK[4][4], accV[4][4], cnt[4];
#pragma unroll
    for (int i = 0; i < 4; i++) {
        cnt[i] = 0.f;
#pragma unroll
        for (int j = 0; j < 4; j++) { accK[i][j] = 0.f; accV[i][j] = 0.f; }
    }

    const int SC = S / CH;           // 512
    const int s_base = chunk * SC;

    for (int s0 = 0; s0 < SC; s0 += 64) {
        __syncthreads();
        // stage 64 K rows + 64 V rows
#pragma unroll
        for (int q = 0; q < 4; q++) {
            int f  = tid + 256 * q;
            int sl = f >> 4, dd = (f & 15) * 4;
            size_t gi = ((size_t)(b * S + s_base + s0 + sl)) * D_MODEL + h * D_HEAD + dd;
            *(f4*)&Kt[sl][dd] = *(const f4*)&Kbuf[gi];
            *(f4*)&Vt[sl][dd] = *(const f4*)&Vbuf[gi];
        }
        __syncthreads();

        // z[l] = K_row . W_bin[l]  (2 l's per lane)
        {
            const int l0 = sub * 2;
            f4 z0 = {0.f, 0.f, 0.f, 0.f}, z1 = {0.f, 0.f, 0.f, 0.f};
#pragma unroll
            for (int d4 = 0; d4 < 16; d4++) {
                f4 kv = *(const f4*)&Kt[row][d4 * 4];
                f4 w0 = *(const f4*)&Wb[l0][d4 * 4];
                f4 w1 = *(const f4*)&Wb[l0 + 1][d4 * 4];
                z0 += kv * w0;
                z1 += kv * w1;
            }
            zsm[row][l0]     = z0[0] + z0[1] + z0[2] + z0[3];
            zsm[row][l0 + 1] = z1[0] + z1[1] + z1[2] + z1[3];
        }
        __syncthreads();

        // logits + softmax over 64 bins (16 bins per lane, 4-lane reduce)
        {
            float zr[8];
#pragma unroll
            for (int l = 0; l < 8; l++) zr[l] = zsm[row][l];
            f4 lg[4];
#pragma unroll
            for (int q = 0; q < 4; q++) lg[q] = (f4){0.f, 0.f, 0.f, 0.f};
#pragma unroll
            for (int l = 0; l < 8; l++) {
                float zv = zr[l];
#pragma unroll
                for (int q = 0; q < 4; q++) {
                    f4 pr = *(const f4*)&Prt[l][sub * 16 + q * 4];
                    lg[q] += zv * pr;
                }
            }
            float mx = -1e30f;
#pragma unroll
            for (int q = 0; q < 4; q++) {
                lg[q] *= scale;
                mx = fmaxf(mx, fmaxf(fmaxf(lg[q][0], lg[q][1]), fmaxf(lg[q][2], lg[q][3])));
            }
            mx = fmaxf(mx, __shfl_xor(mx, 1));
            mx = fmaxf(mx, __shfl_xor(mx, 2));
            float sum = 0.f;
            f4 pv[4];
#pragma unroll
            for (int q = 0; q < 4; q++) {
#pragma unroll
                for (int e = 0; e < 4; e++) {
                    float ev = expf(lg[q][e] - mx);
                    pv[q][e] = ev;
                    sum += ev;
                }
            }
            sum += __shfl_xor(sum, 1);
            sum += __shfl_xor(sum, 2);
            float inv = 1.0f / sum;
#pragma unroll
            for (int q = 0; q < 4; q++) {
                pv[q] *= inv;
                *(f4*)&Pt[row][sub * 16 + q * 4] = pv[q];
            }
        }
        __syncthreads();

        // outer-product accumulate: acc[n][d] += P[s][n]*K[s][d] (and V), cnt[n] += P[s][n]
#pragma unroll 4
        for (int s = 0; s < 64; s++) {
            f4 pp = *(const f4*)&Pt[s][n0];
            f4 kk = *(const f4*)&Kt[s][d0];
            f4 vv = *(const f4*)&Vt[s][d0];
#pragma unroll
            for (int i = 0; i < 4; i++) {
                float p = pp[i];
#pragma unroll
                for (int j = 0; j < 4; j++) {
                    accK[i][j] += p * kk[j];
                    accV[i][j] += p * vv[j];
                }
            }
            if ((tid & 15) == 0) {
#pragma unroll
                for (int i = 0; i < 4; i++) cnt[i] += pp[i];
            }
        }
    }

    float* base = partials + ((size_t)bh * CH + chunk) * 8256;
#pragma unroll
    for (int i = 0; i < 4; i++) {
#pragma unroll
        for (int j = 0; j < 4; j++) {
            base[(size_t)(n0 + i) * 64 + d0 + j]        = accK[i][j];
            base[4096 + (size_t)(n0 + i) * 64 + d0 + j] = accV[i][j];
        }
        if ((tid & 15) == 0) base[8192 + n0 + i] = cnt[i];
    }
}

// ---------------------------------------------------------------------------
// Reduce partials -> K_binned, V_binned.
// FAITHFUL TO REFERENCE BUG: divides feature d by counts[d] (broadcast of
// [B,H,N,Dh]/[B,H,1,N], valid only because Dh==N).
// ---------------------------------------------------------------------------
__global__ __launch_bounds__(256)
void bin_reduce(const float* __restrict__ partials, float* __restrict__ Kb,
                float* __restrict__ Vb, int CH)
{
    const int bh = blockIdx.x;
    const int tid = threadIdx.x;
    __shared__ float inv_cnt[64];
    const float* base = partials + (size_t)bh * CH * 8256;
    if (tid < 64) {
        float c = 0.f;
        for (int ch = 0; ch < CH; ch++) c += base[(size_t)ch * 8256 + 8192 + tid];
        inv_cnt[tid] = 1.0f / (c + 1e-6f);
    }
    __syncthreads();
    for (int idx = tid; idx < 4096; idx += 256) {
        float k = 0.f, v = 0.f;
        for (int ch = 0; ch < CH; ch++) {
            const float* p = base + (size_t)ch * 8256;
            k += p[idx];
            v += p[4096 + idx];
        }
        float ic = inv_cnt[idx & 63];   // divide by count of FEATURE index d
        Kb[(size_t)bh * 4096 + idx] = k * ic;
        Vb[(size_t)bh * 4096 + idx] = v * ic;
    }
}

// ---------------------------------------------------------------------------
// Bin attention: scores = Q.K_binned^T/8, softmax over 64 bins, ctx = w.V_binned.
// grid = (B*H, S/64). 64 Q-rows per block, 4 lanes per row, 16 bins per lane.
// ---------------------------------------------------------------------------
__global__ __launch_bounds__(256)
void bin_attention(const float* __restrict__ Qbuf, const float* __restrict__ Kb,
                   const float* __restrict__ Vb, float* __restrict__ Ctx,
                   int B, int S)
{
    const int bh = blockIdx.x;
    const int h  = bh & (N_HEADS - 1);
    const int b  = bh >> 4;
    const int tid = threadIdx.x;
    const int row = tid >> 2, sub = tid & 3;

    __shared__ __attribute__((aligned(16))) float Kbs[64][68];
    __shared__ __attribute__((aligned(16))) float Vbs[64][68];
    __shared__ __attribute__((aligned(16))) float Qt[64][68];

    const float* kbp = Kb + (size_t)bh * 4096;
    const float* vbp = Vb + (size_t)bh * 4096;
#pragma unroll
    for (int q = 0; q < 4; q++) {
        int f = tid + 256 * q;
        int n = f >> 4, c = (f & 15) * 4;
        *(f4*)&Kbs[n][c] = *(const f4*)&kbp[(size_t)f * 4];
        *(f4*)&Vbs[n][c] = *(const f4*)&vbp[(size_t)f * 4];
    }
    const int s0 = blockIdx.y * 64;
#pragma unroll
    for (int q = 0; q < 4; q++) {
        int f = tid + 256 * q;
        int sl = f >> 4, dd = (f & 15) * 4;
        size_t gi = ((size_t)(b * S + s0 + sl)) * D_MODEL + h * D_HEAD + dd;
        *(f4*)&Qt[sl][dd] = *(const f4*)&Qbuf[gi];
    }
    __syncthreads();

    // scores for this lane's bins n = 4j+sub
    f4 wa[16];
#pragma unroll
    for (int j = 0; j < 16; j++) wa[j] = (f4){0.f, 0.f, 0.f, 0.f};
    for (int d4 = 0; d4 < 16; d4++) {
        f4 qv = *(const f4*)&Qt[row][d4 * 4];
#pragma unroll
        for (int j = 0; j < 16; j++) {
            f4 kk = *(const f4*)&Kbs[4 * j + sub][d4 * 4];
            wa[j] += qv * kk;
        }
    }
    float w[16];
    float mx = -1e30f;
#pragma unroll
    for (int j = 0; j < 16; j++) {
        w[j] = (wa[j][0] + wa[j][1] + wa[j][2] + wa[j][3]) * 0.125f;
        mx = fmaxf(mx, w[j]);
    }
    mx = fmaxf(mx, __shfl_xor(mx, 1));
    mx = fmaxf(mx, __shfl_xor(mx, 2));
    float sum = 0.f;
#pragma unroll
    for (int j = 0; j < 16; j++) {
        w[j] = expf(w[j] - mx);
        sum += w[j];
    }
    sum += __shfl_xor(sum, 1);
    sum += __shfl_xor(sum, 2);
    float inv = 1.0f / sum;

    // stash normalized weights in Qt (Q is dead) so the ctx loop can be
    // dynamically indexed without spilling register arrays (rule #20)
#pragma unroll
    for (int j = 0; j < 16; j++) Qt[row][4 * j + sub] = w[j] * inv;

    f4 ca[16];
#pragma unroll
    for (int q = 0; q < 16; q++) ca[q] = (f4){0.f, 0.f, 0.f, 0.f};
    for (int j = 0; j < 16; j++) {
        float wn = Qt[row][4 * j + sub];
#pragma unroll
        for (int d4 = 0; d4 < 16; d4++) {
            f4 vv = *(const f4*)&Vbs[4 * j + sub][d4 * 4];
            ca[d4] += wn * vv;
        }
    }

    // reduce-scatter across the 4 lanes of this row:
    // after step1 lane keeps its half, after step2 its final quarter.
    const bool low2 = (sub & 2) == 0;
    f4 halfv[8];
#pragma unroll
    for (int q = 0; q < 8; q++) {
#pragma unroll
        for (int e = 0; e < 4; e++) {
            float send = low2 ? ca[8 + q][e] : ca[q][e];
            float recv = __shfl_xor(send, 2);
            float mine = low2 ? ca[q][e] : ca[8 + q][e];
            halfv[q][e] = mine + recv;
        }
    }
    const bool low1 = (sub & 1) == 0;
    f4 quar[4];
#pragma unroll
    for (int q = 0; q < 4; q++) {
#pragma unroll
        for (int e = 0; e < 4; e++) {
            float send = low1 ? halfv[4 + q][e] : halfv[q][e];
            float recv = __shfl_xor(send, 1);
            float mine = low1 ? halfv[q][e] : halfv[4 + q][e];
            quar[q][e] = mine + recv;
        }
    }

    size_t go = ((size_t)(b * S + s0 + row)) * D_MODEL + h * D_HEAD + sub * 16;
#pragma unroll
    for (int q = 0; q < 4; q++) {
        *(f4*)&Ctx[go + q * 4] = quar[q];
    }
}

// ---------------------------------------------------------------------------
extern "C" void kernel_launch(void* const* d_in, const int* in_sizes, int n_in,
                              void* d_out, int out_size, void* d_ws, size_t ws_size,
                              hipStream_t stream)
{
    (void)n_in; (void)out_size; (void)ws_size;
    const float* x       = (const float*)d_in[0];
    const float* Wq      = (const float*)d_in[1];
    const float* bq      = (const float*)d_in[2];
    const float* Wk      = (const float*)d_in[3];
    const float* bk      = (const float*)d_in[4];
    const float* Wv      = (const float*)d_in[5];
    const float* bv      = (const float*)d_in[6];
    const float* Wo      = (const float*)d_in[7];
    const float* bo      = (const float*)d_in[8];
    const float* W_bin   = (const float*)d_in[9];
    const float* proto   = (const float*)d_in[10];
    const float* log_tau = (const float*)d_in[11];
    float* out = (float*)d_out;

    const int M  = in_sizes[0] / D_MODEL;   // B*S = 16384
    const int S  = 4096;
    const int B  = M / S;                   // 4
    const int BH = B * N_HEADS;             // 64
    const int CH = 8;

    float* ws   = (float*)d_ws;
    float* bufA = ws;                               // K, later Q  (M*1024)
    float* bufB = ws + (size_t)M * D_MODEL;         // V, later ctx (M*1024)
    float* part = bufB + (size_t)M * D_MODEL;       // BH*CH*8256
    float* Kb   = part + (size_t)BH * CH * 8256;    // BH*4096
    float* Vb   = Kb + (size_t)BH * 4096;           // BH*4096

    dim3 gg(M / 128, D_MODEL / 128);

    sgemm_nt_bias<<<gg, 256, 0, stream>>>(x, Wk, bk, bufA, M, D_MODEL, D_MODEL);
    sgemm_nt_bias<<<gg, 256, 0, stream>>>(x, Wv, bv, bufB, M, D_MODEL, D_MODEL);
    bin_assign_agg<<<dim3(BH, CH), 256, 0, stream>>>(bufA, bufB, W_bin, proto,
                                                     log_tau, part, B, S);
    bin_reduce<<<BH, 256, 0, stream>>>(part, Kb, Vb, CH);
    sgemm_nt_bias<<<gg, 256, 0, stream>>>(x, Wq, bq, bufA, M, D_MODEL, D_MODEL);
    bin_attention<<<dim3(BH, S / 64), 256, 0, stream>>>(bufA, Kb, Vb, bufB, B, S);
    sgemm_nt_bias<<<gg, 256, 0, stream>>>(bufB, Wo, bo, out, M, D_MODEL, D_MODEL);
}